// Round 10
// baseline (512.526 us; speedup 1.0000x reference)
//
#include <hip/hip_runtime.h>

#define N_NODES 100000
#define N_EDGES 1600000
#define D 64
#define NB 782                 // ceil(100000/128) dst-buckets of 128 nodes
#define CAP 3072               // slab slots per bucket (mean 2048, sigma~45)
#define EPB 8192               // edges per partition block
#define NPART ((N_EDGES + EPB - 1) / EPB)   // 196
#define RSH 14                 // src-range shift: range = src>>14 in 0..6

typedef unsigned short ushort_t;
typedef unsigned int uint_t;

// ---------- K1: repack feat -> bf16 (RNE) + init gcur ----------
__device__ __forceinline__ ushort_t f2bf(float f) {
    uint_t u = __float_as_uint(f);
    u += 0x7FFF + ((u >> 16) & 1);          // round-nearest-even
    return (ushort_t)(u >> 16);
}

__global__ __launch_bounds__(256) void repack_init(const float* __restrict__ feat,
                                                   ushort_t* __restrict__ featb,
                                                   int* __restrict__ gcur) {
    const int tid = blockIdx.x * 256 + threadIdx.x;
    if (tid < NB) gcur[tid] = tid * CAP;
    const int base = tid * 16;              // 16 floats per thread
    if (base >= N_NODES * D) return;
    const float4* f4 = (const float4*)(feat + base);
    ushort4* o4 = (ushort4*)(featb + base);
#pragma unroll
    for (int j = 0; j < 4; ++j) {
        const float4 v = f4[j];
        o4[j] = make_ushort4(f2bf(v.x), f2bf(v.y), f2bf(v.z), f2bf(v.w));
    }
}

// ---------- K2: partition edges into per-bucket slabs (r7 proven) ----------
__global__ __launch_bounds__(1024) void partition(const int* __restrict__ esrc,
                                                  const int* __restrict__ edst,
                                                  int* __restrict__ gcur,
                                                  int* __restrict__ slab) {
    __shared__ int stage[EPB];              // 32 KB: packed, sorted by bucket
    __shared__ ushort_t bkt16[EPB];         // 16 KB: bucket of sorted pos
    __shared__ int cnt[NB];
    __shared__ int cur[NB];
    __shared__ int gb[NB];
    __shared__ int s[1024];
    const int t = threadIdx.x;
    const int base = blockIdx.x * EPB;
    const int n = min(EPB, N_EDGES - base);

    if (t < NB) cnt[t] = 0;
    __syncthreads();
    for (int i = t; i < n; i += 1024)
        atomicAdd(&cnt[edst[base + i] >> 7], 1);
    __syncthreads();
    const int v = (t < NB) ? cnt[t] : 0;
    s[t] = v;
    __syncthreads();
    for (int off = 1; off < 1024; off <<= 1) {
        const int x = (t >= off) ? s[t - off] : 0;
        __syncthreads();
        s[t] += x;
        __syncthreads();
    }
    if (t < NB) {
        const int excl = s[t] - v;          // exclusive prefix
        cur[t] = excl;
        gb[t] = (v ? atomicAdd(&gcur[t], v) : 0) - excl;
    }
    __syncthreads();
    for (int i = t; i < n; i += 1024) {     // coalesced re-read (L2-hot)
        const int d = edst[base + i];
        const int bkt = d >> 7;
        const int pos = atomicAdd(&cur[bkt], 1);
        stage[pos] = ((d & 127) << 17) | esrc[base + i];
        bkt16[pos] = (ushort_t)bkt;
    }
    __syncthreads();
    for (int i = t; i < n; i += 1024) {     // coalesced segment writes
        const int bkt = bkt16[i];
        const int gp = gb[bkt] + i;
        if (gp < (bkt + 1) * CAP)           // overflow guard (never expected)
            slab[gp] = stage[i];
    }
}

// ---------- 8-lane all-reduce on the VALU pipe (DPP, no DS ops) ----------
template<int CTRL>
__device__ __forceinline__ float fadd_dpp(float x) {
    const int r = __builtin_amdgcn_update_dpp(0, __float_as_int(x), CTRL, 0xF, 0xF, true);
    return x + __int_as_float(r);
}
__device__ __forceinline__ float red8(float p) {
    p = fadd_dpp<0xB1>(p);    // quad_perm [1,0,3,2]  : xor 1
    p = fadd_dpp<0x4E>(p);    // quad_perm [2,3,0,1]  : xor 2
    p = fadd_dpp<0x141>(p);   // row_half_mirror      : xor within 8
    return p;
}

// cvt 8 bf16 (uint4) -> g[8] fp32, and dot vs h[8]
__device__ __forceinline__ float cvt_dot(const uint4 u, const float* __restrict__ h,
                                         float* __restrict__ g) {
    g[0] = __uint_as_float(u.x << 16); g[1] = __uint_as_float(u.x & 0xFFFF0000u);
    g[2] = __uint_as_float(u.y << 16); g[3] = __uint_as_float(u.y & 0xFFFF0000u);
    g[4] = __uint_as_float(u.z << 16); g[5] = __uint_as_float(u.z & 0xFFFF0000u);
    g[6] = __uint_as_float(u.w << 16); g[7] = __uint_as_float(u.w & 0xFFFF0000u);
    float p = 0.f;
#pragma unroll
    for (int k = 0; k < 8; ++k) p += g[k] * h[k];
    return p;
}

// ---------- K3: fused SDDMM + SpMM + Linear ----------
// r7 proven structure (depth-2 pipelined edge loop, 44.2us) + GEMM epilogue.
// Fusion discipline learned from r1/r2/r8: NO accumulator survives past its
// own edge loop -- acc is flushed to hN (LDS) immediately, before the next
// loop starts; the GEMM phase starts from fresh register state after one
// barrier. hN[128][68] aliases only phase-A-dead LDS (seA/cnt/cur/s);
// seB/rowoff stay live at non-overlapping offsets. 47.6 KB -> 3 blocks/CU
// (all 782 blocks resident; r9 proved K3 is occupancy-insensitive).
#define SMEM_BYTES 47632
#define OFF_ROW 12288          // rowoff[129] -> ends 12804, pad to 12816
#define OFF_SEA 12816          // seA[3072]   -> ends 25104 (dead after scatter)
#define OFF_CNT 25104          // cnt[1024]   -> ends 29200 (dead)
#define OFF_CUR 29200          // cur[1024]   -> ends 33296 (dead)
#define OFF_S   33296          // s[512]      -> ends 35344 (dead)
#define OFF_HN  12816          // hN[128][68] floats = 34816 -> ends 47632

__global__ __launch_bounds__(512) void fused_spmm_gemm(
        const float4* __restrict__ feat4,
        const uint4* __restrict__ featb4,
        const int* __restrict__ slab,
        const int* __restrict__ gcur,
        const float* __restrict__ W,
        float4* __restrict__ out4) {
    __shared__ __align__(16) char smem[SMEM_BYTES];
    int* seB    = (int*)(smem);                      // live through edge loops
    int* rowoff = (int*)(smem + OFF_ROW);            // live through edge loops
    int* seA    = (int*)(smem + OFF_SEA);
    int* cnt    = (int*)(smem + OFF_CNT);
    int* cur    = (int*)(smem + OFF_CUR);
    int* s      = (int*)(smem + OFF_S);
    float (*hN)[68] = (float(*)[68])(smem + OFF_HN); // aliases seA/cnt/cur/s

    const int t = threadIdx.x;
    const int b = blockIdx.x;
    const int nbase = b << 7;
    const int nb_nodes = min(128, N_NODES - nbase);
    const int sbase = b * CAP;
    const int ne = min(gcur[b] - sbase, CAP);

    // ---- phase A: counting sort by (local_dst, src_range) -- r7 verbatim ----
    for (int i = t; i < ne; i += 512) seA[i] = slab[sbase + i];
    cnt[t] = 0; cnt[t + 512] = 0;
    __syncthreads();
    for (int i = t; i < ne; i += 512) {
        const int pk = seA[i];
        atomicAdd(&cnt[((pk >> 17) << 3) | ((pk & 0x1FFFF) >> RSH)], 1);
    }
    __syncthreads();
    const int v0 = cnt[2 * t], v1 = cnt[2 * t + 1];
    const int sum = v0 + v1;
    s[t] = sum;
    __syncthreads();
    for (int off = 1; off < 512; off <<= 1) {
        const int x = (t >= off) ? s[t - off] : 0;
        __syncthreads();
        s[t] += x;
        __syncthreads();
    }
    const int excl = s[t] - sum;
    cur[2 * t] = excl;
    cur[2 * t + 1] = excl + v0;
    __syncthreads();
    if (t < 128) rowoff[t] = cur[t << 3];
    if (t == 0) rowoff[128] = ne;
    __syncthreads();
    for (int i = t; i < ne; i += 512) {
        const int pk = seA[i];
        const int key = ((pk >> 17) << 3) | ((pk & 0x1FFFF) >> RSH);
        const int pos = atomicAdd(&cur[key], 1);
        seB[pos] = pk & 0x1FFFF;
    }
    __syncthreads();                        // seA/cnt/cur/s dead from here

    // ---- phase B: edge loops (r7 depth-2 body), acc -> hN immediately ----
    const int slot = t >> 3;                // 64 node-slots per block
    const int l = t & 7;                    // lane owns dims 8l..8l+7
#pragma unroll
    for (int ln0 = 0; ln0 < 128; ln0 += 64) {
        const int ln = ln0 + slot;
        if (ln >= nb_nodes) continue;       // no barriers in this loop: safe
        const int nidx = nbase + ln;
        float h[8];
        {
            const float4 ha = feat4[nidx * 16 + 2 * l];
            const float4 hb = feat4[nidx * 16 + 2 * l + 1];
            h[0] = ha.x; h[1] = ha.y; h[2] = ha.z; h[3] = ha.w;
            h[4] = hb.x; h[5] = hb.y; h[6] = hb.z; h[7] = hb.w;
        }
        float acc[8];
#pragma unroll
        for (int k = 0; k < 8; ++k) acc[k] = 0.f;

        int e = rowoff[ln];
        const int e1 = rowoff[ln + 1];
        const int nq = (e1 - e) >> 2;       // number of full quads
        if (nq > 0) {
            // prologue: issue quad 0
            int s0 = seB[e], s1 = seB[e + 1], s2 = seB[e + 2], s3 = seB[e + 3];
            uint4 u0 = featb4[s0 * 8 + l];
            uint4 u1 = featb4[s1 * 8 + l];
            uint4 u2 = featb4[s2 * 8 + l];
            uint4 u3 = featb4[s3 * 8 + l];
            for (int q = 1; q < nq; ++q) {
                // issue quad q BEFORE processing quad q-1 (8 loads in flight)
                const int eb = e + q * 4;
                const int t0 = seB[eb], t1 = seB[eb + 1];
                const int t2 = seB[eb + 2], t3 = seB[eb + 3];
                const uint4 w0 = featb4[t0 * 8 + l];
                const uint4 w1 = featb4[t1 * 8 + l];
                const uint4 w2 = featb4[t2 * 8 + l];
                const uint4 w3 = featb4[t3 * 8 + l];
                float g0[8], g1[8], g2[8], g3[8];
                float p0 = cvt_dot(u0, h, g0);
                float p1 = cvt_dot(u1, h, g1);
                float p2 = cvt_dot(u2, h, g2);
                float p3 = cvt_dot(u3, h, g3);
                p0 = red8(p0); p1 = red8(p1); p2 = red8(p2); p3 = red8(p3);
#pragma unroll
                for (int k = 0; k < 8; ++k)
                    acc[k] += g0[k] * p0 + g1[k] * p1 + g2[k] * p2 + g3[k] * p3;
                u0 = w0; u1 = w1; u2 = w2; u3 = w3;
            }
            {   // epilogue: process final quad
                float g0[8], g1[8], g2[8], g3[8];
                float p0 = cvt_dot(u0, h, g0);
                float p1 = cvt_dot(u1, h, g1);
                float p2 = cvt_dot(u2, h, g2);
                float p3 = cvt_dot(u3, h, g3);
                p0 = red8(p0); p1 = red8(p1); p2 = red8(p2); p3 = red8(p3);
#pragma unroll
                for (int k = 0; k < 8; ++k)
                    acc[k] += g0[k] * p0 + g1[k] * p1 + g2[k] * p2 + g3[k] * p3;
            }
            e += nq * 4;
        }
        for (; e < e1; ++e) {
            const uint4 u0 = featb4[seB[e] * 8 + l];
            float g0[8];
            float p0 = red8(cvt_dot(u0, h, g0));
#pragma unroll
            for (int k = 0; k < 8; ++k) acc[k] += g0[k] * p0;
        }
        // flush accumulator to LDS NOW -- nothing survives this loop iter
        *(float4*)&hN[ln][8 * l]     = make_float4(acc[0], acc[1], acc[2], acc[3]);
        *(float4*)&hN[ln][8 * l + 4] = make_float4(acc[4], acc[5], acc[6], acc[7]);
    }
    __syncthreads();                        // hN complete (128 rows)

    // ---- phase C: GEMM out[row,:] = hN[row,:] @ W^T (fresh registers) ----
    // thread: 4 rows x 4 cols. W read from global (16 KB, L1-resident).
    {
        const float4* W4 = (const float4*)W;
        const int c4 = (t & 15) * 4;
        const int r0 = (t >> 4) * 4;        // t>>4 in 0..31 -> rows 0..124
        float a[4][4];
#pragma unroll
        for (int r = 0; r < 4; ++r)
#pragma unroll
            for (int c = 0; c < 4; ++c) a[r][c] = 0.f;

        for (int i4 = 0; i4 < 16; ++i4) {
            const float4 w0 = W4[(c4 + 0) * 16 + i4];
            const float4 w1 = W4[(c4 + 1) * 16 + i4];
            const float4 w2 = W4[(c4 + 2) * 16 + i4];
            const float4 w3 = W4[(c4 + 3) * 16 + i4];
#pragma unroll
            for (int r = 0; r < 4; ++r) {
                const float4 x = *(const float4*)&hN[r0 + r][i4 * 4];
                a[r][0] += x.x * w0.x + x.y * w0.y + x.z * w0.z + x.w * w0.w;
                a[r][1] += x.x * w1.x + x.y * w1.y + x.z * w1.z + x.w * w1.w;
                a[r][2] += x.x * w2.x + x.y * w2.y + x.z * w2.z + x.w * w2.w;
                a[r][3] += x.x * w3.x + x.y * w3.y + x.z * w3.z + x.w * w3.w;
            }
        }
#pragma unroll
        for (int r = 0; r < 4; ++r) {
            const int rr = r0 + r;
            if (rr < nb_nodes)
                out4[(long)(nbase + rr) * 16 + (t & 15)] =
                    make_float4(a[r][0], a[r][1], a[r][2], a[r][3]);
        }
    }
}

extern "C" void kernel_launch(void* const* d_in, const int* in_sizes, int n_in,
                              void* d_out, int out_size, void* d_ws, size_t ws_size,
                              hipStream_t stream) {
    const float* feat = (const float*)d_in[0];
    const int*   esrc = (const int*)d_in[1];
    const int*   edst = (const int*)d_in[2];
    const float* W    = (const float*)d_in[3];
    float* out = (float*)d_out;

    char* ws = (char*)d_ws;
    ushort_t* featb = (ushort_t*)(ws);                       // 12.8 MB
    int* slab = (int*)(ws + 12800000);                       // NB*CAP*4 = 9.61 MB
    int* gcur = (int*)(ws + 12800000 + (size_t)NB * CAP * 4);// 3.1 KB

    repack_init<<<(N_NODES * D / 16 + 255) / 256, 256, 0, stream>>>(feat, featb, gcur);
    partition<<<NPART, 1024, 0, stream>>>(esrc, edst, gcur, slab);
    fused_spmm_gemm<<<NB, 512, 0, stream>>>((const float4*)feat, (const uint4*)featb,
                                            slab, gcur, W, (float4*)out);
}